// Round 8
// baseline (374.512 us; speedup 1.0000x reference)
//
#include <hip/hip_runtime.h>

#define CAP 128

typedef __attribute__((ext_vector_type(8))) short bf16x8;
typedef __attribute__((ext_vector_type(4))) float f32x4;
typedef __attribute__((ext_vector_type(4))) float f32x4v;

__device__ __forceinline__ unsigned short f2bf(float f) {
    unsigned u = __float_as_uint(f);
    u += 0x7FFFu + ((u >> 16) & 1u);
    return (unsigned short)(u >> 16);
}
__device__ __forceinline__ float bf2f(unsigned short h) {
    return __uint_as_float(((unsigned)h) << 16);
}

// ---------------- fp32 -> bf16 conversion (hp, hq, 12 weights) ----------------
struct CvtSeg { const float* s; unsigned short* d; int n4; };
struct CvtArgs { CvtSeg seg[14]; };

__global__ __launch_bounds__(256) void cvt_kernel(CvtArgs c) {
    int gid = blockIdx.x * 256 + threadIdx.x;
    int stride = gridDim.x * 256;
    #pragma unroll
    for (int si = 0; si < 14; ++si) {
        CvtSeg sg = c.seg[si];
        for (int i = gid; i < sg.n4; i += stride) {
            float4 v = ((const float4*)sg.s)[i];
            ushort4 o;
            o.x = f2bf(v.x); o.y = f2bf(v.y); o.z = f2bf(v.z); o.w = f2bf(v.w);
            ((ushort4*)sg.d)[i] = o;
        }
    }
}

// ---------------- extract body (at HBM roofline) ----------------
struct ExtArgs { const float* a0; const float* a1; const float* a2; const float* a3; int* idx; int* cnt; };

__device__ __forceinline__ void extract_body(const ExtArgs& e, int row, int m) {
    int t = threadIdx.x;
    int wave = t >> 6, lane = t & 63;
    const float* A = (m == 0) ? e.a0 : (m == 1) ? e.a1 : (m == 2) ? e.a2 : e.a3;
    const f32x4v* rp = (const f32x4v*)(A + (size_t)row * 8192);
    unsigned mask = 0;
    #pragma unroll
    for (int it = 0; it < 8; ++it) {
        f32x4v v = __builtin_nontemporal_load(&rp[it * 256 + t]);
        mask |= (unsigned)(v.x != 0.f) << (4 * it);
        mask |= (unsigned)(v.y != 0.f) << (4 * it + 1);
        mask |= (unsigned)(v.z != 0.f) << (4 * it + 2);
        mask |= (unsigned)(v.w != 0.f) << (4 * it + 3);
    }
    int cnt = __popc(mask);
    int pre = cnt;
    #pragma unroll
    for (int off = 1; off < 64; off <<= 1) {
        int u = __shfl_up(pre, off);
        if (lane >= off) pre += u;
    }
    __shared__ int lwt[4];
    if (lane == 63) lwt[wave] = pre;
    __syncthreads();
    int wbase = 0;
    if (wave > 0) wbase += lwt[0];
    if (wave > 1) wbase += lwt[1];
    if (wave > 2) wbase += lwt[2];
    int o = wbase + pre - cnt;
    int* op = e.idx + ((size_t)m * 8192 + row) * CAP;
    while (mask) {
        int b = __ffs((int)mask) - 1;
        mask &= mask - 1;
        int j = (b >> 2) * 1024 + t * 4 + (b & 3);
        if (o < CAP) op[o] = j;
        o++;
    }
    if (t == 0) {
        int tot = lwt[0] + lwt[1] + lwt[2] + lwt[3];
        e.cnt[m * 8192 + row] = tot < CAP ? tot : CAP;
    }
}

// ---------------- slim gemm body: acc[2][2], ~40 VGPR ----------------
struct GemmDesc { const unsigned short* X; const unsigned short* W; const float* bias; unsigned short* Z; };
struct GemmArgs { GemmDesc d[6]; };

template<int K>
__device__ __forceinline__ void gemm_slim_body(const GemmArgs& ga, int bx, int by, int bz) {
    GemmDesc g = ga.d[bz];
    int wave = threadIdx.x >> 6;
    int lane = threadIdx.x & 63;
    int r = lane & 15, q = lane >> 4;
    int rowbase = bx * 128 + wave * 32;
    int colbase = by * 32;
    f32x4 acc[2][2] = {};
    const unsigned short* xp0 = g.X + (size_t)(rowbase + r) * K + q * 8;
    const unsigned short* xp1 = xp0 + (size_t)16 * K;
    const unsigned short* wb0 = g.W + (size_t)(colbase + r) * K + q * 8;
    const unsigned short* wb1 = wb0 + (size_t)16 * K;
    #pragma unroll 4
    for (int k0 = 0; k0 < K; k0 += 32) {
        bf16x8 a0 = *(const bf16x8*)(xp0 + k0);
        bf16x8 a1 = *(const bf16x8*)(xp1 + k0);
        bf16x8 b0 = *(const bf16x8*)(wb0 + k0);
        bf16x8 b1 = *(const bf16x8*)(wb1 + k0);
        acc[0][0] = __builtin_amdgcn_mfma_f32_16x16x32_bf16(a0, b0, acc[0][0], 0, 0, 0);
        acc[0][1] = __builtin_amdgcn_mfma_f32_16x16x32_bf16(a0, b1, acc[0][1], 0, 0, 0);
        acc[1][0] = __builtin_amdgcn_mfma_f32_16x16x32_bf16(a1, b0, acc[1][0], 0, 0, 0);
        acc[1][1] = __builtin_amdgcn_mfma_f32_16x16x32_bf16(a1, b1, acc[1][1], 0, 0, 0);
    }
    #pragma unroll
    for (int mt = 0; mt < 2; ++mt) {
        #pragma unroll
        for (int nt = 0; nt < 2; ++nt) {
            int col = colbase + nt * 16 + r;
            float bv = g.bias[col];
            #pragma unroll
            for (int j = 0; j < 4; ++j) {
                int row = rowbase + mt * 16 + q * 4 + j;
                g.Z[(size_t)row * 256 + col] = f2bf(acc[mt][nt][j] + bv);
            }
        }
    }
}

// ---------------- fused: extract (32768) + layer-1 gemm (3072, slim) ----------------
__global__ __launch_bounds__(256, 8) void fused_ext_gemm_kernel(ExtArgs e, GemmArgs ga) {
    int bid = blockIdx.x;
    int gemmIdx = -1, extIdx;
    if (bid < 27648) {
        int grp = bid / 9, rem = bid % 9;
        if (rem == 0) gemmIdx = grp;
        extIdx = grp * 8 + (rem - 1);
    } else {
        extIdx = 24576 + (bid - 27648);
    }
    if (gemmIdx >= 0) {
        gemm_slim_body<512>(ga, gemmIdx & 63, (gemmIdx >> 6) & 7, gemmIdx >> 9);
    } else {
        extract_body(e, extIdx & 8191, extIdx >> 13);
    }
}

// standalone gemm for layer 2 (runs alone, VGPR free)
template<int K>
__global__ __launch_bounds__(256) void gemm6_kernel(GemmArgs ga) {
    GemmDesc g = ga.d[blockIdx.z];
    int wave = threadIdx.x >> 6;
    int lane = threadIdx.x & 63;
    int r = lane & 15, q = lane >> 4;
    int rowbase = blockIdx.x * 128 + wave * 32;
    int colbase = blockIdx.y * 64;
    f32x4 acc[2][4] = {};
    const unsigned short* xp0 = g.X + (size_t)(rowbase + r) * K + q * 8;
    const unsigned short* xp1 = xp0 + (size_t)16 * K;
    const unsigned short* wbase = g.W + (size_t)(colbase + r) * K + q * 8;
    #pragma unroll
    for (int k0 = 0; k0 < K; k0 += 32) {
        bf16x8 a0 = *(const bf16x8*)(xp0 + k0);
        bf16x8 a1 = *(const bf16x8*)(xp1 + k0);
        #pragma unroll
        for (int nt = 0; nt < 4; ++nt) {
            bf16x8 b = *(const bf16x8*)(wbase + (size_t)nt * 16 * K + k0);
            acc[0][nt] = __builtin_amdgcn_mfma_f32_16x16x32_bf16(a0, b, acc[0][nt], 0, 0, 0);
            acc[1][nt] = __builtin_amdgcn_mfma_f32_16x16x32_bf16(a1, b, acc[1][nt], 0, 0, 0);
        }
    }
    #pragma unroll
    for (int mt = 0; mt < 2; ++mt) {
        #pragma unroll
        for (int nt = 0; nt < 4; ++nt) {
            int col = colbase + nt * 16 + r;
            float bv = g.bias[col];
            #pragma unroll
            for (int j = 0; j < 4; ++j) {
                int row = rowbase + mt * 16 + q * 4 + j;
                g.Z[(size_t)row * 256 + col] = f2bf(acc[mt][nt][j] + bv);
            }
        }
    }
}

// ---------------- column-panel agg with XCD L2 affinity ----------------
// Block = 32 rows x 64-col panel (128 B, line-aligned). bid%8 = side*4+panel
// so (by wgid%8->XCD round-robin) each XCD serves one (side,panel): za+zb
// panel working set = 2 MB -> fits 4 MiB XCD L2; gathers served at L2 rate
// instead of LLC. 8-lane unit per row: one 128 B line per neighbor gather.
// FINAL: writes unnormalized fp32 + per-(row,panel) sumsq partial; norm_kernel
// rescales d_out in place.
struct AggSide {
    const unsigned short* zself;
    const unsigned short* za;
    const unsigned short* zb;
    const int* idxa; const int* cnta;
    const int* idxb; const int* cntb;
    unsigned short* out_bf;
    float* out_f;
};

template<int FINAL>
__global__ __launch_bounds__(256) void agg_kernel(AggSide s0, AggSide s1, float* partial) {
    int bid = blockIdx.x;
    int side = (bid >> 2) & 1;
    int panel = bid & 3;
    int chunk = bid >> 3;                  // 256 chunks
    AggSide s = side ? s1 : s0;
    int t = threadIdx.x;
    int unit = t >> 3, l8 = t & 7;         // 32 row-units x 8 lanes
    int row = chunk * 32 + unit;
    int col = panel * 64 + l8 * 8;         // 8 bf16 (16 B) per lane
    bf16x8 v = *(const bf16x8*)(s.zself + (size_t)row * 256 + col);
    float acc[8];
    #pragma unroll
    for (int j = 0; j < 8; ++j) acc[j] = bf2f((unsigned short)v[j]);
    int ca = s.cnta[row], cb = s.cntb[row];
    const int* ia = s.idxa + (size_t)row * CAP;
    const int* ib = s.idxb + (size_t)row * CAP;
    #pragma unroll 4
    for (int k = 0; k < ca; ++k) {
        int na = ia[k];                    // uniform within unit -> L1 broadcast
        bf16x8 w = *(const bf16x8*)(s.za + (size_t)na * 256 + col);
        #pragma unroll
        for (int j = 0; j < 8; ++j) acc[j] += bf2f((unsigned short)w[j]);
    }
    #pragma unroll 4
    for (int k = 0; k < cb; ++k) {
        int nb = ib[k];
        bf16x8 w = *(const bf16x8*)(s.zb + (size_t)nb * 256 + col);
        #pragma unroll
        for (int j = 0; j < 8; ++j) acc[j] += bf2f((unsigned short)w[j]);
    }
    #pragma unroll
    for (int j = 0; j < 8; ++j) acc[j] = acc[j] > 0.f ? acc[j] : 0.1f * acc[j];
    if (FINAL) {
        float ss = 0.f;
        #pragma unroll
        for (int j = 0; j < 8; ++j) ss += acc[j] * acc[j];
        #pragma unroll
        for (int off = 1; off < 8; off <<= 1) ss += __shfl_xor(ss, off);   // within 8-lane unit
        float* op = s.out_f + (size_t)row * 256 + col;                     // unnormalized
        float4 o0, o1;
        o0.x = acc[0]; o0.y = acc[1]; o0.z = acc[2]; o0.w = acc[3];
        o1.x = acc[4]; o1.y = acc[5]; o1.z = acc[6]; o1.w = acc[7];
        *(float4*)op = o0;
        *(float4*)(op + 4) = o1;
        if (l8 == 0) partial[((size_t)(side * 8192 + row)) * 4 + panel] = ss;
    } else {
        bf16x8 o;
        #pragma unroll
        for (int j = 0; j < 8; ++j) o[j] = (short)f2bf(acc[j]);
        *(bf16x8*)(s.out_bf + (size_t)row * 256 + col) = o;
    }
}

// ---------------- in-place row L2-normalize of d_out ----------------
__global__ __launch_bounds__(256) void norm_kernel(float* out, const float* partial) {
    int t = threadIdx.x;
    int unit = t >> 3, l8 = t & 7;
    int row = blockIdx.x * 32 + unit;      // 512 blocks * 32 rows = 16384
    const float* pp = partial + (size_t)row * 4;
    float ss = pp[0] + pp[1] + pp[2] + pp[3];
    float sc = 1.0f / (sqrtf(ss) + 1e-9f);
    float4* rp = (float4*)(out + (size_t)row * 256) + l8 * 8;   // 8 float4 per lane
    #pragma unroll
    for (int j = 0; j < 8; ++j) {
        float4 v = rp[j];
        v.x *= sc; v.y *= sc; v.z *= sc; v.w *= sc;
        rp[j] = v;
    }
}

extern "C" void kernel_launch(void* const* d_in, const int* in_sizes, int n_in,
                              void* d_out, int out_size, void* d_ws, size_t ws_size,
                              hipStream_t stream) {
    const float* hp         = (const float*)d_in[0];
    const float* hq         = (const float*)d_in[1];
    const float* a_cons     = (const float*)d_in[2];
    const float* a_prod     = (const float*)d_in[3];
    const float* a_rev_cons = (const float*)d_in[4];
    const float* a_rev_prod = (const float*)d_in[5];

    char* ws = (char*)d_ws;
    constexpr size_t SZ_H   = (size_t)8192 * 512 * 2;   // bf16 hp/hq
    constexpr size_t SZ_W1  = (size_t)256 * 512 * 2;
    constexpr size_t SZ_W2  = (size_t)256 * 256 * 2;
    constexpr size_t SZ_Z   = (size_t)8192 * 256 * 2;   // bf16 z / h1
    constexpr size_t OFF_HP  = 0;
    constexpr size_t OFF_HQ  = OFF_HP + SZ_H;
    constexpr size_t OFF_WBF = OFF_HQ + SZ_H;
    constexpr size_t OFF_IDX = OFF_WBF + 6 * SZ_W1 + 6 * SZ_W2;
    constexpr size_t OFF_CNT = OFF_IDX + (size_t)4 * 8192 * CAP * 4;
    constexpr size_t OFF_Z   = OFF_CNT + (size_t)4 * 8192 * 4;
    constexpr size_t OFF_H1P = OFF_Z + 6 * SZ_Z;
    constexpr size_t OFF_H1Q = OFF_H1P + SZ_Z;
    constexpr size_t OFF_PART = OFF_H1Q + SZ_Z;         // 16384 x 4 fp32 partial sumsq

    unsigned short* hp_bf = (unsigned short*)(ws + OFF_HP);
    unsigned short* hq_bf = (unsigned short*)(ws + OFF_HQ);
    int* idx = (int*)(ws + OFF_IDX);
    int* cnt = (int*)(ws + OFF_CNT);
    unsigned short* z[6];
    for (int i = 0; i < 6; ++i) z[i] = (unsigned short*)(ws + OFF_Z + i * SZ_Z);
    unsigned short* h1p = (unsigned short*)(ws + OFF_H1P);
    unsigned short* h1q = (unsigned short*)(ws + OFF_H1Q);
    float* partial = (float*)(ws + OFF_PART);

    unsigned short* wbf[12];
    for (int i = 0; i < 6; ++i) wbf[i]     = (unsigned short*)(ws + OFF_WBF + i * SZ_W1);
    for (int i = 0; i < 6; ++i) wbf[6 + i] = (unsigned short*)(ws + OFF_WBF + 6 * SZ_W1 + i * SZ_W2);

    CvtArgs ca;
    ca.seg[0] = { hp, hp_bf, 8192 * 512 / 4 };
    ca.seg[1] = { hq, hq_bf, 8192 * 512 / 4 };
    const int wIdxL1[6] = { 6, 10, 12, 8, 14, 16 };   // wp1, wcons1, wrprod1, wq1, wprod1, wrcons1
    const int wIdxL2[6] = { 18, 22, 24, 20, 26, 28 }; // wp2, wcons2, wrprod2, wq2, wprod2, wrcons2
    for (int i = 0; i < 6; ++i) ca.seg[2 + i] = { (const float*)d_in[wIdxL1[i]], wbf[i],     256 * 512 / 4 };
    for (int i = 0; i < 6; ++i) ca.seg[8 + i] = { (const float*)d_in[wIdxL2[i]], wbf[6 + i], 256 * 256 / 4 };
    cvt_kernel<<<dim3(1024), dim3(256), 0, stream>>>(ca);

    // fused: extract (1.07 GB HBM stream) + layer-1 linears (slim, interleaved 1:9)
    ExtArgs ea = { a_cons, a_prod, a_rev_cons, a_rev_prod, idx, cnt };
    GemmArgs g1;
    g1.d[0] = { hp_bf, wbf[0], (const float*)d_in[7],  z[0] };
    g1.d[1] = { hq_bf, wbf[1], (const float*)d_in[11], z[1] };
    g1.d[2] = { hq_bf, wbf[2], (const float*)d_in[13], z[2] };
    g1.d[3] = { hq_bf, wbf[3], (const float*)d_in[9],  z[3] };
    g1.d[4] = { hp_bf, wbf[4], (const float*)d_in[15], z[4] };
    g1.d[5] = { hp_bf, wbf[5], (const float*)d_in[17], z[5] };
    fused_ext_gemm_kernel<<<dim3(35840), dim3(256), 0, stream>>>(ea, g1);

    int* idx0 = idx + (size_t)0 * 8192 * CAP;  // a_cons      (P rows over Q)
    int* idx1 = idx + (size_t)1 * 8192 * CAP;  // a_prod      (Q rows over P)
    int* idx2 = idx + (size_t)2 * 8192 * CAP;  // a_rev_cons  (Q rows over P)
    int* idx3 = idx + (size_t)3 * 8192 * CAP;  // a_rev_prod  (P rows over Q)
    int* cnt0 = cnt, *cnt1 = cnt + 8192, *cnt2 = cnt + 16384, *cnt3 = cnt + 24576;

    AggSide p1 = { z[0], z[1], z[2], idx0, cnt0, idx3, cnt3, h1p, nullptr };
    AggSide q1 = { z[3], z[4], z[5], idx1, cnt1, idx2, cnt2, h1q, nullptr };
    agg_kernel<0><<<dim3(2048), dim3(256), 0, stream>>>(p1, q1, nullptr);

    // layer 2 linears (K=256)
    GemmArgs g2;
    g2.d[0] = { h1p, wbf[6],  (const float*)d_in[19], z[0] };
    g2.d[1] = { h1q, wbf[7],  (const float*)d_in[23], z[1] };
    g2.d[2] = { h1q, wbf[8],  (const float*)d_in[25], z[2] };
    g2.d[3] = { h1q, wbf[9],  (const float*)d_in[21], z[3] };
    g2.d[4] = { h1p, wbf[10], (const float*)d_in[27], z[4] };
    g2.d[5] = { h1p, wbf[11], (const float*)d_in[29], z[5] };
    gemm6_kernel<256><<<dim3(64, 4, 6), dim3(256), 0, stream>>>(g2);

    float* outp = (float*)d_out;
    AggSide p2 = { z[0], z[1], z[2], idx0, cnt0, idx3, cnt3, nullptr, outp };
    AggSide q2 = { z[3], z[4], z[5], idx1, cnt1, idx2, cnt2, nullptr, outp + (size_t)8192 * 256 };
    agg_kernel<1><<<dim3(2048), dim3(256), 0, stream>>>(p2, q2, partial);
    norm_kernel<<<dim3(512), dim3(256), 0, stream>>>(outp, partial);
}

// Round 9
// 308.615 us; speedup vs baseline: 1.2135x; 1.2135x over previous
//
#include <hip/hip_runtime.h>

#define CAP 128

typedef __attribute__((ext_vector_type(8))) short bf16x8;
typedef __attribute__((ext_vector_type(4))) float f32x4;
typedef __attribute__((ext_vector_type(4))) float f32x4v;

__device__ __forceinline__ unsigned short f2bf(float f) {
    unsigned u = __float_as_uint(f);
    u += 0x7FFFu + ((u >> 16) & 1u);
    return (unsigned short)(u >> 16);
}
__device__ __forceinline__ float bf2f(unsigned short h) {
    return __uint_as_float(((unsigned)h) << 16);
}

// ---------------- fp32 -> bf16 conversion (hp, hq, 12 weights) ----------------
struct CvtSeg { const float* s; unsigned short* d; int n4; };
struct CvtArgs { CvtSeg seg[14]; };

__global__ __launch_bounds__(256) void cvt_kernel(CvtArgs c) {
    int gid = blockIdx.x * 256 + threadIdx.x;
    int stride = gridDim.x * 256;
    #pragma unroll
    for (int si = 0; si < 14; ++si) {
        CvtSeg sg = c.seg[si];
        for (int i = gid; i < sg.n4; i += stride) {
            float4 v = ((const float4*)sg.s)[i];
            ushort4 o;
            o.x = f2bf(v.x); o.y = f2bf(v.y); o.z = f2bf(v.z); o.w = f2bf(v.w);
            ((ushort4*)sg.d)[i] = o;
        }
    }
}

// ---------------- dense 0/1 adjacency -> per-row index lists (97% of HBM roofline) ----------------
struct ExtArgs { const float* a0; const float* a1; const float* a2; const float* a3; int* idx; int* cnt; };

__global__ __launch_bounds__(256) void extract_kernel(ExtArgs e) {
    int row = blockIdx.x, m = blockIdx.y, t = threadIdx.x;
    int wave = t >> 6, lane = t & 63;
    const float* A = (m == 0) ? e.a0 : (m == 1) ? e.a1 : (m == 2) ? e.a2 : e.a3;
    const f32x4v* rp = (const f32x4v*)(A + (size_t)row * 8192);
    unsigned mask = 0;
    #pragma unroll
    for (int it = 0; it < 8; ++it) {
        f32x4v v = __builtin_nontemporal_load(&rp[it * 256 + t]);
        mask |= (unsigned)(v.x != 0.f) << (4 * it);
        mask |= (unsigned)(v.y != 0.f) << (4 * it + 1);
        mask |= (unsigned)(v.z != 0.f) << (4 * it + 2);
        mask |= (unsigned)(v.w != 0.f) << (4 * it + 3);
    }
    int cnt = __popc(mask);
    int pre = cnt;
    #pragma unroll
    for (int off = 1; off < 64; off <<= 1) {
        int u = __shfl_up(pre, off);
        if (lane >= off) pre += u;
    }
    __shared__ int lwt[4];
    if (lane == 63) lwt[wave] = pre;
    __syncthreads();
    int wbase = 0;
    if (wave > 0) wbase += lwt[0];
    if (wave > 1) wbase += lwt[1];
    if (wave > 2) wbase += lwt[2];
    int o = wbase + pre - cnt;
    int* op = e.idx + ((size_t)m * 8192 + row) * CAP;
    while (mask) {
        int b = __ffs((int)mask) - 1;
        mask &= mask - 1;
        int j = (b >> 2) * 1024 + t * 4 + (b & 3);
        if (o < CAP) op[o] = j;
        o++;
    }
    if (t == 0) {
        int tot = lwt[0] + lwt[1] + lwt[2] + lwt[3];
        e.cnt[m * 8192 + row] = tot < CAP ? tot : CAP;
    }
}

// ---------------- LDS-tiled gemm: Z = bf16(X @ W^T + b) ----------------
// 128x128 tile, 4 waves (2x2), each wave 64x64 = 4x4 16x16x32 fragments.
// BK=64 reg-staged through LDS with 16B-chunk XOR swizzle (chunk ^= row&7)
// applied on BOTH write and read (rule 21) -> 8 evenly-spread bank starts.
// Replaces the ~200 TF direct-global fat tile (6 L2 loads per 8 MFMA).
struct GemmDesc { const unsigned short* X; const unsigned short* W; const float* bias; unsigned short* Z; };
struct GemmArgs { GemmDesc d[6]; };

template<int K>
__global__ __launch_bounds__(256) void gemm_lds_kernel(GemmArgs ga) {
    GemmDesc g = ga.d[blockIdx.z];
    __shared__ unsigned short Asm[128 * 64];
    __shared__ unsigned short Bsm[128 * 64];
    int t = threadIdx.x;
    int wave = t >> 6, lane = t & 63;
    int r = lane & 15, q = lane >> 4;
    int wr = wave >> 1, wc = wave & 1;
    int rowbase = blockIdx.x * 128;       // 64 x-blocks
    int colbase = blockIdx.y * 128;       // 2 y-blocks (N=256)
    // staging: 1024 16B slots per tile; thread t covers s = t + 256*i
    const unsigned short* gA[4];
    const unsigned short* gB[4];
    int ls[4];
    #pragma unroll
    for (int i = 0; i < 4; ++i) {
        int s = t + 256 * i;
        int srow = s >> 3, c = s & 7;
        gA[i] = g.X + (size_t)(rowbase + srow) * K + c * 8;
        gB[i] = g.W + (size_t)(colbase + srow) * K + c * 8;
        ls[i] = srow * 64 + ((c ^ (srow & 7)) * 8);
    }
    f32x4 acc[4][4] = {};
    for (int k0 = 0; k0 < K; k0 += 64) {
        #pragma unroll
        for (int i = 0; i < 4; ++i) {
            *(bf16x8*)&Asm[ls[i]] = *(const bf16x8*)(gA[i] + k0);
            *(bf16x8*)&Bsm[ls[i]] = *(const bf16x8*)(gB[i] + k0);
        }
        __syncthreads();
        #pragma unroll
        for (int ks = 0; ks < 2; ++ks) {
            bf16x8 af[4], bfr[4];
            #pragma unroll
            for (int m = 0; m < 4; ++m)
                af[m] = *(const bf16x8*)&Asm[(wr * 64 + m * 16 + r) * 64 + (((ks * 4 + q) ^ (r & 7)) * 8)];
            #pragma unroll
            for (int n = 0; n < 4; ++n)
                bfr[n] = *(const bf16x8*)&Bsm[(wc * 64 + n * 16 + r) * 64 + (((ks * 4 + q) ^ (r & 7)) * 8)];
            #pragma unroll
            for (int m = 0; m < 4; ++m) {
                #pragma unroll
                for (int n = 0; n < 4; ++n)
                    acc[m][n] = __builtin_amdgcn_mfma_f32_16x16x32_bf16(af[m], bfr[n], acc[m][n], 0, 0, 0);
            }
        }
        __syncthreads();
    }
    // C/D layout: col = lane&15, row = (lane>>4)*4 + reg
    #pragma unroll
    for (int n = 0; n < 4; ++n) {
        int col = colbase + wc * 64 + n * 16 + r;
        float bv = g.bias[col];
        #pragma unroll
        for (int m = 0; m < 4; ++m) {
            int rowb = rowbase + wr * 64 + m * 16 + q * 4;
            #pragma unroll
            for (int j = 0; j < 4; ++j)
                g.Z[(size_t)(rowb + j) * 256 + col] = f2bf(acc[m][n][j] + bv);
        }
    }
}

// ---------------- fused self + 2 SpMM gathers + leaky_relu (+ optional L2-norm) ----------------
// R6 form: 32 lanes per output row (16 B/lane), direct uniform index loads
// (L1 broadcast), separate a/b loops unroll 4.
struct AggSide {
    const unsigned short* zself;
    const unsigned short* za;
    const unsigned short* zb;
    const int* idxa; const int* cnta;
    const int* idxb; const int* cntb;
    unsigned short* out_bf;
    float* out_f;
};

template<int FINAL>
__global__ __launch_bounds__(256) void agg_kernel(AggSide s0, AggSide s1) {
    AggSide s = blockIdx.y ? s1 : s0;
    int t = threadIdx.x;
    int l32 = t & 31;
    int row = blockIdx.x * 8 + (t >> 5);   // 1024 blocks * 8 rows per side
    int c8 = l32 * 8;                      // 8 bf16 cols (16 B) per lane
    bf16x8 v = *(const bf16x8*)(s.zself + (size_t)row * 256 + c8);
    float acc[8];
    #pragma unroll
    for (int j = 0; j < 8; ++j) acc[j] = bf2f((unsigned short)v[j]);
    int ca = s.cnta[row], cb = s.cntb[row];
    const int* ia = s.idxa + (size_t)row * CAP;
    const int* ib = s.idxb + (size_t)row * CAP;
    #pragma unroll 4
    for (int k = 0; k < ca; ++k) {
        int na = ia[k];
        bf16x8 w = *(const bf16x8*)(s.za + (size_t)na * 256 + c8);
        #pragma unroll
        for (int j = 0; j < 8; ++j) acc[j] += bf2f((unsigned short)w[j]);
    }
    #pragma unroll 4
    for (int k = 0; k < cb; ++k) {
        int nb = ib[k];
        bf16x8 w = *(const bf16x8*)(s.zb + (size_t)nb * 256 + c8);
        #pragma unroll
        for (int j = 0; j < 8; ++j) acc[j] += bf2f((unsigned short)w[j]);
    }
    #pragma unroll
    for (int j = 0; j < 8; ++j) acc[j] = acc[j] > 0.f ? acc[j] : 0.1f * acc[j];
    if (FINAL) {
        float ss = 0.f;
        #pragma unroll
        for (int j = 0; j < 8; ++j) ss += acc[j] * acc[j];
        #pragma unroll
        for (int off = 1; off < 32; off <<= 1) ss += __shfl_xor(ss, off);
        float sc = 1.0f / (sqrtf(ss) + 1e-9f);
        float4 o0, o1;
        o0.x = acc[0] * sc; o0.y = acc[1] * sc; o0.z = acc[2] * sc; o0.w = acc[3] * sc;
        o1.x = acc[4] * sc; o1.y = acc[5] * sc; o1.z = acc[6] * sc; o1.w = acc[7] * sc;
        float* op = s.out_f + (size_t)row * 256 + c8;
        *(float4*)op = o0;
        *(float4*)(op + 4) = o1;
    } else {
        bf16x8 o;
        #pragma unroll
        for (int j = 0; j < 8; ++j) o[j] = (short)f2bf(acc[j]);
        *(bf16x8*)(s.out_bf + (size_t)row * 256 + c8) = o;
    }
}

extern "C" void kernel_launch(void* const* d_in, const int* in_sizes, int n_in,
                              void* d_out, int out_size, void* d_ws, size_t ws_size,
                              hipStream_t stream) {
    const float* hp         = (const float*)d_in[0];
    const float* hq         = (const float*)d_in[1];
    const float* a_cons     = (const float*)d_in[2];
    const float* a_prod     = (const float*)d_in[3];
    const float* a_rev_cons = (const float*)d_in[4];
    const float* a_rev_prod = (const float*)d_in[5];

    char* ws = (char*)d_ws;
    constexpr size_t SZ_H   = (size_t)8192 * 512 * 2;   // bf16 hp/hq
    constexpr size_t SZ_W1  = (size_t)256 * 512 * 2;
    constexpr size_t SZ_W2  = (size_t)256 * 256 * 2;
    constexpr size_t SZ_Z   = (size_t)8192 * 256 * 2;   // bf16 z / h1
    constexpr size_t OFF_HP  = 0;
    constexpr size_t OFF_HQ  = OFF_HP + SZ_H;
    constexpr size_t OFF_WBF = OFF_HQ + SZ_H;
    constexpr size_t OFF_IDX = OFF_WBF + 6 * SZ_W1 + 6 * SZ_W2;
    constexpr size_t OFF_CNT = OFF_IDX + (size_t)4 * 8192 * CAP * 4;
    constexpr size_t OFF_Z   = OFF_CNT + (size_t)4 * 8192 * 4;
    constexpr size_t OFF_H1P = OFF_Z + 6 * SZ_Z;
    constexpr size_t OFF_H1Q = OFF_H1P + SZ_Z;

    unsigned short* hp_bf = (unsigned short*)(ws + OFF_HP);
    unsigned short* hq_bf = (unsigned short*)(ws + OFF_HQ);
    int* idx = (int*)(ws + OFF_IDX);
    int* cnt = (int*)(ws + OFF_CNT);
    unsigned short* z[6];
    for (int i = 0; i < 6; ++i) z[i] = (unsigned short*)(ws + OFF_Z + i * SZ_Z);
    unsigned short* h1p = (unsigned short*)(ws + OFF_H1P);
    unsigned short* h1q = (unsigned short*)(ws + OFF_H1Q);

    unsigned short* wbf[12];
    for (int i = 0; i < 6; ++i) wbf[i]     = (unsigned short*)(ws + OFF_WBF + i * SZ_W1);
    for (int i = 0; i < 6; ++i) wbf[6 + i] = (unsigned short*)(ws + OFF_WBF + 6 * SZ_W1 + i * SZ_W2);

    CvtArgs ca;
    ca.seg[0] = { hp, hp_bf, 8192 * 512 / 4 };
    ca.seg[1] = { hq, hq_bf, 8192 * 512 / 4 };
    const int wIdxL1[6] = { 6, 10, 12, 8, 14, 16 };   // wp1, wcons1, wrprod1, wq1, wprod1, wrcons1
    const int wIdxL2[6] = { 18, 22, 24, 20, 26, 28 }; // wp2, wcons2, wrprod2, wq2, wprod2, wrcons2
    for (int i = 0; i < 6; ++i) ca.seg[2 + i] = { (const float*)d_in[wIdxL1[i]], wbf[i],     256 * 512 / 4 };
    for (int i = 0; i < 6; ++i) ca.seg[8 + i] = { (const float*)d_in[wIdxL2[i]], wbf[6 + i], 256 * 256 / 4 };
    cvt_kernel<<<dim3(1024), dim3(256), 0, stream>>>(ca);

    ExtArgs ea = { a_cons, a_prod, a_rev_cons, a_rev_prod, idx, cnt };
    extract_kernel<<<dim3(8192, 4), dim3(256), 0, stream>>>(ea);

    // layer 1 linears (K=512)
    GemmArgs g1;
    g1.d[0] = { hp_bf, wbf[0], (const float*)d_in[7],  z[0] };
    g1.d[1] = { hq_bf, wbf[1], (const float*)d_in[11], z[1] };
    g1.d[2] = { hq_bf, wbf[2], (const float*)d_in[13], z[2] };
    g1.d[3] = { hq_bf, wbf[3], (const float*)d_in[9],  z[3] };
    g1.d[4] = { hp_bf, wbf[4], (const float*)d_in[15], z[4] };
    g1.d[5] = { hp_bf, wbf[5], (const float*)d_in[17], z[5] };
    gemm_lds_kernel<512><<<dim3(64, 2, 6), dim3(256), 0, stream>>>(g1);

    int* idx0 = idx + (size_t)0 * 8192 * CAP;  // a_cons      (P rows over Q)
    int* idx1 = idx + (size_t)1 * 8192 * CAP;  // a_prod      (Q rows over P)
    int* idx2 = idx + (size_t)2 * 8192 * CAP;  // a_rev_cons  (Q rows over P)
    int* idx3 = idx + (size_t)3 * 8192 * CAP;  // a_rev_prod  (P rows over Q)
    int* cnt0 = cnt, *cnt1 = cnt + 8192, *cnt2 = cnt + 16384, *cnt3 = cnt + 24576;

    AggSide p1 = { z[0], z[1], z[2], idx0, cnt0, idx3, cnt3, h1p, nullptr };
    AggSide q1 = { z[3], z[4], z[5], idx1, cnt1, idx2, cnt2, h1q, nullptr };
    agg_kernel<0><<<dim3(1024, 2), dim3(256), 0, stream>>>(p1, q1);

    // layer 2 linears (K=256)
    GemmArgs g2;
    g2.d[0] = { h1p, wbf[6],  (const float*)d_in[19], z[0] };
    g2.d[1] = { h1q, wbf[7],  (const float*)d_in[23], z[1] };
    g2.d[2] = { h1q, wbf[8],  (const float*)d_in[25], z[2] };
    g2.d[3] = { h1q, wbf[9],  (const float*)d_in[21], z[3] };
    g2.d[4] = { h1p, wbf[10], (const float*)d_in[27], z[4] };
    g2.d[5] = { h1p, wbf[11], (const float*)d_in[29], z[5] };
    gemm_lds_kernel<256><<<dim3(64, 2, 6), dim3(256), 0, stream>>>(g2);

    float* outp = (float*)d_out;
    AggSide p2 = { z[0], z[1], z[2], idx0, cnt0, idx3, cnt3, nullptr, outp };
    AggSide q2 = { z[3], z[4], z[5], idx1, cnt1, idx2, cnt2, nullptr, outp + (size_t)8192 * 256 };
    agg_kernel<1><<<dim3(1024, 2), dim3(256), 0, stream>>>(p2, q2);
}

// Round 10
// 306.374 us; speedup vs baseline: 1.2224x; 1.0073x over previous
//
#include <hip/hip_runtime.h>

#define CAP 128

typedef __attribute__((ext_vector_type(8))) short bf16x8;
typedef __attribute__((ext_vector_type(4))) float f32x4;
typedef __attribute__((ext_vector_type(4))) float f32x4v;

// global -> LDS direct (16B/lane). LDS dest is WAVE-UNIFORM base + lane*16;
// global src is per-lane (pre-swizzled). [guide §5, m97/m104/m173]
#define GLOAD16(gp, lp) __builtin_amdgcn_global_load_lds( \
    (const __attribute__((address_space(1))) void*)(gp), \
    (__attribute__((address_space(3))) void*)(lp), 16, 0, 0)

__device__ __forceinline__ unsigned short f2bf(float f) {
    unsigned u = __float_as_uint(f);
    u += 0x7FFFu + ((u >> 16) & 1u);
    return (unsigned short)(u >> 16);
}
__device__ __forceinline__ float bf2f(unsigned short h) {
    return __uint_as_float(((unsigned)h) << 16);
}

// ---------------- fp32 -> bf16 conversion (hp, hq, 12 weights) ----------------
struct CvtSeg { const float* s; unsigned short* d; int n4; };
struct CvtArgs { CvtSeg seg[14]; };

__global__ __launch_bounds__(256) void cvt_kernel(CvtArgs c) {
    int gid = blockIdx.x * 256 + threadIdx.x;
    int stride = gridDim.x * 256;
    #pragma unroll
    for (int si = 0; si < 14; ++si) {
        CvtSeg sg = c.seg[si];
        for (int i = gid; i < sg.n4; i += stride) {
            float4 v = ((const float4*)sg.s)[i];
            ushort4 o;
            o.x = f2bf(v.x); o.y = f2bf(v.y); o.z = f2bf(v.z); o.w = f2bf(v.w);
            ((ushort4*)sg.d)[i] = o;
        }
    }
}

// ---------------- dense 0/1 adjacency -> per-row index lists (97% of HBM roofline) ----------------
struct ExtArgs { const float* a0; const float* a1; const float* a2; const float* a3; int* idx; int* cnt; };

__global__ __launch_bounds__(256) void extract_kernel(ExtArgs e) {
    int row = blockIdx.x, m = blockIdx.y, t = threadIdx.x;
    int wave = t >> 6, lane = t & 63;
    const float* A = (m == 0) ? e.a0 : (m == 1) ? e.a1 : (m == 2) ? e.a2 : e.a3;
    const f32x4v* rp = (const f32x4v*)(A + (size_t)row * 8192);
    unsigned mask = 0;
    #pragma unroll
    for (int it = 0; it < 8; ++it) {
        f32x4v v = __builtin_nontemporal_load(&rp[it * 256 + t]);
        mask |= (unsigned)(v.x != 0.f) << (4 * it);
        mask |= (unsigned)(v.y != 0.f) << (4 * it + 1);
        mask |= (unsigned)(v.z != 0.f) << (4 * it + 2);
        mask |= (unsigned)(v.w != 0.f) << (4 * it + 3);
    }
    int cnt = __popc(mask);
    int pre = cnt;
    #pragma unroll
    for (int off = 1; off < 64; off <<= 1) {
        int u = __shfl_up(pre, off);
        if (lane >= off) pre += u;
    }
    __shared__ int lwt[4];
    if (lane == 63) lwt[wave] = pre;
    __syncthreads();
    int wbase = 0;
    if (wave > 0) wbase += lwt[0];
    if (wave > 1) wbase += lwt[1];
    if (wave > 2) wbase += lwt[2];
    int o = wbase + pre - cnt;
    int* op = e.idx + ((size_t)m * 8192 + row) * CAP;
    while (mask) {
        int b = __ffs((int)mask) - 1;
        mask &= mask - 1;
        int j = (b >> 2) * 1024 + t * 4 + (b & 3);
        if (o < CAP) op[o] = j;
        o++;
    }
    if (t == 0) {
        int tot = lwt[0] + lwt[1] + lwt[2] + lwt[3];
        e.cnt[m * 8192 + row] = tot < CAP ? tot : CAP;
    }
}

// ---------------- LDS-tiled gemm, global_load_lds staging ----------------
// 128x128 tile, 4 waves (2x2), wave = 64x64 (4x4 16x16x32 fragments), BK=64.
// Staging: linear LDS dest + INVERSE-swizzled per-lane global src (rule 21 /
// m173): lane l stages src chunk (l&7)^(l>>3), so Asm[row][p] = X[row][p^(row&7)].
// Read side (unchanged from verified R9): chunk (ks*4+q)^(r&7) -> conflict-free.
struct GemmDesc { const unsigned short* X; const unsigned short* W; const float* bias; unsigned short* Z; };
struct GemmArgs { GemmDesc d[6]; };

template<int K>
__global__ __launch_bounds__(256) void gemm_lds_kernel(GemmArgs ga) {
    GemmDesc g = ga.d[blockIdx.z];
    __shared__ __align__(16) unsigned short Asm[128 * 64];
    __shared__ __align__(16) unsigned short Bsm[128 * 64];
    int t = threadIdx.x;
    int wave = t >> 6, lane = t & 63;
    int r = lane & 15, q = lane >> 4;
    int wr = wave >> 1, wc = wave & 1;
    int rowbase = blockIdx.x * 128;       // 64 x-blocks
    int colbase = blockIdx.y * 128;       // 2 y-blocks (N=256)
    // per-instr: 64 lanes x 16 B = 8 rows of 128 B; 4 waves x 4 instrs = 128 rows
    int srcchunk = (lane & 7) ^ (lane >> 3);          // inverse swizzle in source
    const unsigned short* gAl[4];
    const unsigned short* gBl[4];
    unsigned loff[4];
    #pragma unroll
    for (int i = 0; i < 4; ++i) {
        int row = wave * 32 + i * 8 + (lane >> 3);
        gAl[i] = g.X + (size_t)(rowbase + row) * K + srcchunk * 8;
        gBl[i] = g.W + (size_t)(colbase + row) * K + srcchunk * 8;
        loff[i] = (unsigned)(wave * 32 + i * 8) * 128;   // byte base, wave-uniform
    }
    f32x4 acc[4][4] = {};
    for (int k0 = 0; k0 < K; k0 += 64) {
        #pragma unroll
        for (int i = 0; i < 4; ++i) {
            GLOAD16(gAl[i] + k0, (char*)Asm + loff[i]);
            GLOAD16(gBl[i] + k0, (char*)Bsm + loff[i]);
        }
        __syncthreads();                  // drains vmcnt -> staged tile visible
        #pragma unroll
        for (int ks = 0; ks < 2; ++ks) {
            bf16x8 af[4], bfr[4];
            #pragma unroll
            for (int m = 0; m < 4; ++m)
                af[m] = *(const bf16x8*)&Asm[(wr * 64 + m * 16 + r) * 64 + (((ks * 4 + q) ^ (r & 7)) * 8)];
            #pragma unroll
            for (int n = 0; n < 4; ++n)
                bfr[n] = *(const bf16x8*)&Bsm[(wc * 64 + n * 16 + r) * 64 + (((ks * 4 + q) ^ (r & 7)) * 8)];
            #pragma unroll
            for (int m = 0; m < 4; ++m) {
                #pragma unroll
                for (int n = 0; n < 4; ++n)
                    acc[m][n] = __builtin_amdgcn_mfma_f32_16x16x32_bf16(af[m], bfr[n], acc[m][n], 0, 0, 0);
            }
        }
        __syncthreads();
    }
    // C/D layout: col = lane&15, row = (lane>>4)*4 + reg
    #pragma unroll
    for (int n = 0; n < 4; ++n) {
        int col = colbase + wc * 64 + n * 16 + r;
        float bv = g.bias[col];
        #pragma unroll
        for (int m = 0; m < 4; ++m) {
            int rowb = rowbase + wr * 64 + m * 16 + q * 4;
            #pragma unroll
            for (int j = 0; j < 4; ++j)
                g.Z[(size_t)(rowb + j) * 256 + col] = f2bf(acc[m][n][j] + bv);
        }
    }
}

// ---------------- fused self + 2 SpMM gathers + leaky_relu (+ optional L2-norm) ----------------
// 32 lanes per output row (16 B/lane), direct uniform index loads (L1
// broadcast), separate a/b loops unroll 4. (LLC gather-service bound.)
struct AggSide {
    const unsigned short* zself;
    const unsigned short* za;
    const unsigned short* zb;
    const int* idxa; const int* cnta;
    const int* idxb; const int* cntb;
    unsigned short* out_bf;
    float* out_f;
};

template<int FINAL>
__global__ __launch_bounds__(256) void agg_kernel(AggSide s0, AggSide s1) {
    AggSide s = blockIdx.y ? s1 : s0;
    int t = threadIdx.x;
    int l32 = t & 31;
    int row = blockIdx.x * 8 + (t >> 5);   // 1024 blocks * 8 rows per side
    int c8 = l32 * 8;                      // 8 bf16 cols (16 B) per lane
    bf16x8 v = *(const bf16x8*)(s.zself + (size_t)row * 256 + c8);
    float acc[8];
    #pragma unroll
    for (int j = 0; j < 8; ++j) acc[j] = bf2f((unsigned short)v[j]);
    int ca = s.cnta[row], cb = s.cntb[row];
    const int* ia = s.idxa + (size_t)row * CAP;
    const int* ib = s.idxb + (size_t)row * CAP;
    #pragma unroll 4
    for (int k = 0; k < ca; ++k) {
        int na = ia[k];
        bf16x8 w = *(const bf16x8*)(s.za + (size_t)na * 256 + c8);
        #pragma unroll
        for (int j = 0; j < 8; ++j) acc[j] += bf2f((unsigned short)w[j]);
    }
    #pragma unroll 4
    for (int k = 0; k < cb; ++k) {
        int nb = ib[k];
        bf16x8 w = *(const bf16x8*)(s.zb + (size_t)nb * 256 + c8);
        #pragma unroll
        for (int j = 0; j < 8; ++j) acc[j] += bf2f((unsigned short)w[j]);
    }
    #pragma unroll
    for (int j = 0; j < 8; ++j) acc[j] = acc[j] > 0.f ? acc[j] : 0.1f * acc[j];
    if (FINAL) {
        float ss = 0.f;
        #pragma unroll
        for (int j = 0; j < 8; ++j) ss += acc[j] * acc[j];
        #pragma unroll
        for (int off = 1; off < 32; off <<= 1) ss += __shfl_xor(ss, off);
        float sc = 1.0f / (sqrtf(ss) + 1e-9f);
        float4 o0, o1;
        o0.x = acc[0] * sc; o0.y = acc[1] * sc; o0.z = acc[2] * sc; o0.w = acc[3] * sc;
        o1.x = acc[4] * sc; o1.y = acc[5] * sc; o1.z = acc[6] * sc; o1.w = acc[7] * sc;
        float* op = s.out_f + (size_t)row * 256 + c8;
        *(float4*)op = o0;
        *(float4*)(op + 4) = o1;
    } else {
        bf16x8 o;
        #pragma unroll
        for (int j = 0; j < 8; ++j) o[j] = (short)f2bf(acc[j]);
        *(bf16x8*)(s.out_bf + (size_t)row * 256 + c8) = o;
    }
}

extern "C" void kernel_launch(void* const* d_in, const int* in_sizes, int n_in,
                              void* d_out, int out_size, void* d_ws, size_t ws_size,
                              hipStream_t stream) {
    const float* hp         = (const float*)d_in[0];
    const float* hq         = (const float*)d_in[1];
    const float* a_cons     = (const float*)d_in[2];
    const float* a_prod     = (const float*)d_in[3];
    const float* a_rev_cons = (const float*)d_in[4];
    const float* a_rev_prod = (const float*)d_in[5];

    char* ws = (char*)d_ws;
    constexpr size_t SZ_H   = (size_t)8192 * 512 * 2;   // bf16 hp/hq
    constexpr size_t SZ_W1  = (size_t)256 * 512 * 2;
    constexpr size_t SZ_W2  = (size_t)256 * 256 * 2;
    constexpr size_t SZ_Z   = (size_t)8192 * 256 * 2;   // bf16 z / h1
    constexpr size_t OFF_HP  = 0;
    constexpr size_t OFF_HQ  = OFF_HP + SZ_H;
    constexpr size_t OFF_WBF = OFF_HQ + SZ_H;
    constexpr size_t OFF_IDX = OFF_WBF + 6 * SZ_W1 + 6 * SZ_W2;
    constexpr size_t OFF_CNT = OFF_IDX + (size_t)4 * 8192 * CAP * 4;
    constexpr size_t OFF_Z   = OFF_CNT + (size_t)4 * 8192 * 4;
    constexpr size_t OFF_H1P = OFF_Z + 6 * SZ_Z;
    constexpr size_t OFF_H1Q = OFF_H1P + SZ_Z;

    unsigned short* hp_bf = (unsigned short*)(ws + OFF_HP);
    unsigned short* hq_bf = (unsigned short*)(ws + OFF_HQ);
    int* idx = (int*)(ws + OFF_IDX);
    int* cnt = (int*)(ws + OFF_CNT);
    unsigned short* z[6];
    for (int i = 0; i < 6; ++i) z[i] = (unsigned short*)(ws + OFF_Z + i * SZ_Z);
    unsigned short* h1p = (unsigned short*)(ws + OFF_H1P);
    unsigned short* h1q = (unsigned short*)(ws + OFF_H1Q);

    unsigned short* wbf[12];
    for (int i = 0; i < 6; ++i) wbf[i]     = (unsigned short*)(ws + OFF_WBF + i * SZ_W1);
    for (int i = 0; i < 6; ++i) wbf[6 + i] = (unsigned short*)(ws + OFF_WBF + 6 * SZ_W1 + i * SZ_W2);

    CvtArgs ca;
    ca.seg[0] = { hp, hp_bf, 8192 * 512 / 4 };
    ca.seg[1] = { hq, hq_bf, 8192 * 512 / 4 };
    const int wIdxL1[6] = { 6, 10, 12, 8, 14, 16 };   // wp1, wcons1, wrprod1, wq1, wprod1, wrcons1
    const int wIdxL2[6] = { 18, 22, 24, 20, 26, 28 }; // wp2, wcons2, wrprod2, wq2, wprod2, wrcons2
    for (int i = 0; i < 6; ++i) ca.seg[2 + i] = { (const float*)d_in[wIdxL1[i]], wbf[i],     256 * 512 / 4 };
    for (int i = 0; i < 6; ++i) ca.seg[8 + i] = { (const float*)d_in[wIdxL2[i]], wbf[6 + i], 256 * 256 / 4 };
    cvt_kernel<<<dim3(1024), dim3(256), 0, stream>>>(ca);

    ExtArgs ea = { a_cons, a_prod, a_rev_cons, a_rev_prod, idx, cnt };
    extract_kernel<<<dim3(8192, 4), dim3(256), 0, stream>>>(ea);

    // layer 1 linears (K=512)
    GemmArgs g1;
    g1.d[0] = { hp_bf, wbf[0], (const float*)d_in[7],  z[0] };
    g1.d[1] = { hq_bf, wbf[1], (const float*)d_in[11], z[1] };
    g1.d[2] = { hq_bf, wbf[2], (const float*)d_in[13], z[2] };
    g1.d[3] = { hq_bf, wbf[3], (const float*)d_in[9],  z[3] };
    g1.d[4] = { hp_bf, wbf[4], (const float*)d_in[15], z[4] };
    g1.d[5] = { hp_bf, wbf[5], (const float*)d_in[17], z[5] };
    gemm_lds_kernel<512><<<dim3(64, 2, 6), dim3(256), 0, stream>>>(g1);

    int* idx0 = idx + (size_t)0 * 8192 * CAP;  // a_cons      (P rows over Q)
    int* idx1 = idx + (size_t)1 * 8192 * CAP;  // a_prod      (Q rows over P)
    int* idx2 = idx + (size_t)2 * 8192 * CAP;  // a_rev_cons  (Q rows over P)
    int* idx3 = idx + (size_t)3 * 8192 * CAP;  // a_rev_prod  (P rows over Q)
    int* cnt0 = cnt, *cnt1 = cnt + 8192, *cnt2 = cnt + 16384, *cnt3 = cnt + 24576;

    AggSide p1 = { z[0], z[1], z[2], idx0, cnt0, idx3, cnt3, h1p, nullptr };
    AggSide q1 = { z[3], z[4], z[5], idx1, cnt1, idx2, cnt2, h1q, nullptr };
    agg_kernel<0><<<dim3(1024, 2), dim3(256), 0, stream>>>(p1, q1);

    // layer 2 linears (K=256)
    GemmArgs g2;
    g2.d[0] = { h1p, wbf[6],  (const float*)d_in[19], z[0] };
    g2.d[1] = { h1q, wbf[7],  (const float*)d_in[23], z[1] };
    g2.d[2] = { h1q, wbf[8],  (const float*)d_in[25], z[2] };
    g2.d[3] = { h1q, wbf[9],  (const float*)d_in[21], z[3] };
    g2.d[4] = { h1p, wbf[10], (const float*)d_in[27], z[4] };
    g2.d[5] = { h1p, wbf[11], (const float*)d_in[29], z[5] };
    gemm_lds_kernel<256><<<dim3(64, 2, 6), dim3(256), 0, stream>>>(g2);

    float* outp = (float*)d_out;
    AggSide p2 = { z[0], z[1], z[2], idx0, cnt0, idx3, cnt3, nullptr, outp };
    AggSide q2 = { z[3], z[4], z[5], idx1, cnt1, idx2, cnt2, nullptr, outp + (size_t)8192 * 256 };
    agg_kernel<1><<<dim3(1024, 2), dim3(256), 0, stream>>>(p2, q2);
}